// Round 13
// baseline (1092.582 us; speedup 1.0000x reference)
//
#include <hip/hip_runtime.h>
#include <math.h>

#define B_   64
#define S_   1024
#define DK_  128
#define DV_  128
#define LR_    0.1f
#define THR_   0.1f
#define ITEMP_ 10.0f
#define EPS_   1e-6f
#define LRP1_  1.1f   // 1 + LR

// ---- DPP helpers ----
template<int CTRL>
__device__ __forceinline__ float dpp_add(float x) {
  int t = __builtin_amdgcn_update_dpp(0, __float_as_int(x), CTRL, 0xf, 0xf, true);
  return x + __int_as_float(t);
}
__device__ __forceinline__ float wave_sum64(float x) {
  x = dpp_add<0x111>(x); x = dpp_add<0x112>(x); x = dpp_add<0x114>(x);
  x = dpp_add<0x118>(x); x = dpp_add<0x142>(x); x = dpp_add<0x143>(x);
  return __int_as_float(__builtin_amdgcn_readlane(__float_as_int(x), 63));
}
__device__ __forceinline__ float quad_sum4(float x) {
  x = dpp_add<0xB1>(x); x = dpp_add<0x4E>(x);
  return x;
}
// sum of 8 values held in lanes (lane&7) slots: 3 row_shr adds, total in lane 7
__device__ __forceinline__ float oct_sum(float x) {
  x = dpp_add<0x111>(x); x = dpp_add<0x112>(x); x = dpp_add<0x114>(x);
  return __int_as_float(__builtin_amdgcn_readlane(__float_as_int(x), 7));
}

__device__ __forceinline__ void gll16(const float* g, float* l) {
  __builtin_amdgcn_global_load_lds(
      (const __attribute__((address_space(1))) unsigned int*)g,
      (__attribute__((address_space(3))) unsigned int*)l, 16, 0, 0);
}

__global__ __launch_bounds__(512, 2)
void sgm_kernel(const float* __restrict__ mem_in,
                const float* __restrict__ key,
                const float* __restrict__ value,
                float* __restrict__ out) {
  const int b    = blockIdx.x;
  const int tid  = threadIdx.x;
  const int r    = tid >> 2;        // row 0..127
  const int q    = tid & 3;         // owns float4 chunks 4i+q
  const int lane = tid & 63;
  const int wv   = tid >> 6;        // wave 0..7

  __shared__ float  ldsK[8][DK_];
  __shared__ float  ldsV[8][DV_];
  __shared__ float4 ldsR[2][8];     // [parity][wave] = {P,Q,R,-} partials
  __shared__ float  gateL[S_];

  float m[32];
  {
    const float4* mp4 = reinterpret_cast<const float4*>(mem_in + ((size_t)b*DV_ + r)*DK_);
    #pragma unroll
    for (int i = 0; i < 8; ++i) {
      float4 t = mp4[4*i + q];
      m[4*i+0]=t.x; m[4*i+1]=t.y; m[4*i+2]=t.z; m[4*i+3]=t.w;
    }
  }

  const float* kb = key   + (size_t)b * S_ * DK_;
  const float* vb = value + (size_t)b * S_ * DV_;

  auto stageK = [&](int j) {
    if (wv == 0 && lane < 32) gll16(kb + (size_t)j*DK_ + lane*4, &ldsK[j & 7][0]);
  };
  auto stageV = [&](int j) {
    if (wv == 1 && lane < 32) gll16(vb + (size_t)j*DV_ + lane*4, &ldsV[j & 7][0]);
  };

  // zero slot 7 (read by step-0's update with coeff 0 — must be finite)
  if (tid < DK_) ldsK[7][tid] = 0.f;

  stageK(0); stageK(1); stageK(2); stageK(3);
  stageV(0); stageV(1); stageV(2); stageV(3);
  if (wv < 2) asm volatile("s_waitcnt vmcnt(0)" ::: "memory");
  __syncthreads();

  // ---- prologue: step-0 precomputation ----
  float kaC = ldsK[0][lane], kbC = ldsK[0][64+lane];
  float rinC = 1.0f / (sqrtf(wave_sum64(kaC*kaC + kbC*kbC)) + EPS_);
  float rawC;
  {
    const float4* kp4 = reinterpret_cast<const float4*>(&ldsK[0][0]);
    float d0=0,d1=0,d2=0,d3=0;
    #pragma unroll
    for (int i = 0; i < 8; ++i) {
      float4 t = kp4[4*i + q];
      d0=fmaf(m[4*i+0],t.x,d0); d1=fmaf(m[4*i+1],t.y,d1);
      d2=fmaf(m[4*i+2],t.z,d2); d3=fmaf(m[4*i+3],t.w,d3);
    }
    rawC = quad_sum4((d0+d1)+(d2+d3));
  }
  const float vC0 = ldsV[0][r];
  float p0 = fmaf(rinC, rawC, -vC0);
  float aC = fmaf(LRP1_, p0, vC0);      // alpha_0
  float bC = 0.f;                        // beta_0 (u_{-1}=0)
  {
    const float wsP = wave_sum64(p0 * p0);
    if (lane == 0) ldsR[1][wv] = make_float4(wsP, 0.f, 0.f, 0.f);
  }
  asm volatile("s_waitcnt lgkmcnt(0)" ::: "memory");
  __builtin_amdgcn_s_barrier();
  asm volatile("" ::: "memory");
  float P, Q, R;
  {
    const float4 pr = ldsR[1][lane & 7];
    P = 0.25f * oct_sum(pr.x); Q = 0.25f * oct_sum(pr.y); R = 0.25f * oct_sum(pr.z);
  }
  float dkC = 0.f, g1 = 0.f, rin1 = 0.f, u1 = 0.f;

  for (int s = 0; s < S_; ++s) {
    // ---- HEAD: pure scalar gate chain (no cross-lane, no LDS) ----
    const float cd = (g1 * rin1) * dkC;
    const float s2 = fmaxf(fmaf(cd*cd, R, fmaf(-2.0f*cd, Q, P)), 0.f);
    const float g  = 1.0f / (1.0f + __expf((THR_ - sqrtf(s2)) * ITEMP_));
    if (tid == 0) gateL[s] = g;

    // ---- BULK ----
    const float u  = fmaf(-cd, bC, aC);      // u_s
    const float a1 = (g1 * rin1) * u1;       // pending update coeff (step s-1)
    const int ps = (s + 7) & 7, ns = (s + 1) & 7;

    {  // m -= a1 * k_{s-1}
      const float4* kp4 = reinterpret_cast<const float4*>(&ldsK[ps][0]);
      #pragma unroll
      for (int i = 0; i < 8; ++i) {
        float4 t = kp4[4*i + q];
        m[4*i+0]=fmaf(-a1,t.x,m[4*i+0]); m[4*i+1]=fmaf(-a1,t.y,m[4*i+1]);
        m[4*i+2]=fmaf(-a1,t.z,m[4*i+2]); m[4*i+3]=fmaf(-a1,t.w,m[4*i+3]);
      }
    }

    float rawN;
    {  // raw_{s+1} = M_{s-1} . k_{s+1}
      const float4* kp4 = reinterpret_cast<const float4*>(&ldsK[ns][0]);
      float d0=0,d1=0,d2=0,d3=0;
      #pragma unroll
      for (int i = 0; i < 8; ++i) {
        float4 t = kp4[4*i + q];
        d0=fmaf(m[4*i+0],t.x,d0); d1=fmaf(m[4*i+1],t.y,d1);
        d2=fmaf(m[4*i+2],t.z,d2); d3=fmaf(m[4*i+3],t.w,d3);
      }
      rawN = quad_sum4((d0+d1)+(d2+d3));
    }

    const float kaN = ldsK[ns][lane], kbN = ldsK[ns][64+lane];
    const float vN  = ldsV[ns][r];
    const float dkN  = wave_sum64(kaC*kaN + kbC*kbN);
    const float rinN = 1.0f / (sqrtf(wave_sum64(kaN*kaN + kbN*kbN)) + EPS_);

    const float p0N = fmaf(rinN, rawN, -vN);
    const float p1N = rinN * u;
    const float aN  = fmaf(LRP1_, p0N, vN);
    const float bN  = LRP1_ * p1N;

    const float wsP = wave_sum64(p0N * p0N);
    const float wsQ = wave_sum64(p0N * p1N);
    const float wsR = wave_sum64(p1N * p1N);
    if (lane == 0) ldsR[s & 1][wv] = make_float4(wsP, wsQ, wsR, 0.f);

    if ((s & 3) == 0) {  // stage batch s+4..s+7 (clamped)
      const int t0 = s+4 > S_-1 ? S_-1 : s+4, t1 = s+5 > S_-1 ? S_-1 : s+5;
      const int t2 = s+6 > S_-1 ? S_-1 : s+6, t3 = s+7 > S_-1 ? S_-1 : s+7;
      stageK(t0); stageK(t1); stageK(t2); stageK(t3);
      stageV(t0); stageV(t1); stageV(t2); stageV(t3);
    }
    if (((s & 3) == 2) && wv < 2)
      asm volatile("s_waitcnt vmcnt(0)" ::: "memory");  // batch old by ~2 steps

    asm volatile("s_waitcnt lgkmcnt(0)" ::: "memory");
    __builtin_amdgcn_s_barrier();                      // vmcnt stays in flight
    asm volatile("" ::: "memory");

    {
      const float4 pr = ldsR[s & 1][lane & 7];
      P = 0.25f * oct_sum(pr.x); Q = 0.25f * oct_sum(pr.y); R = 0.25f * oct_sum(pr.z);
    }
    g1 = g; rin1 = rinC; rinC = rinN; dkC = dkN;
    u1 = u; aC = aN; bC = bN; kaC = kaN; kbC = kbN;
  }

  // final pending update (step S-1): k_{1023} in slot 7
  {
    const float a1 = (g1 * rin1) * u1;
    const float4* kp4 = reinterpret_cast<const float4*>(&ldsK[7][0]);
    #pragma unroll
    for (int i = 0; i < 8; ++i) {
      float4 t = kp4[4*i + q];
      m[4*i+0]=fmaf(-a1,t.x,m[4*i+0]); m[4*i+1]=fmaf(-a1,t.y,m[4*i+1]);
      m[4*i+2]=fmaf(-a1,t.z,m[4*i+2]); m[4*i+3]=fmaf(-a1,t.w,m[4*i+3]);
    }
  }

  __syncthreads();

  float4* op4 = reinterpret_cast<float4*>(out + ((size_t)b*DV_ + r)*DK_);
  #pragma unroll
  for (int i = 0; i < 8; ++i)
    op4[4*i + q] = make_float4(m[4*i+0], m[4*i+1], m[4*i+2], m[4*i+3]);

  float* go = out + (size_t)B_ * DV_ * DK_ + (size_t)b * S_;
  reinterpret_cast<float2*>(go)[tid] = reinterpret_cast<const float2*>(gateL)[tid];
}

extern "C" void kernel_launch(void* const* d_in, const int* in_sizes, int n_in,
                              void* d_out, int out_size, void* d_ws, size_t ws_size,
                              hipStream_t stream) {
  const float* mem = (const float*)d_in[0];
  const float* key = (const float*)d_in[1];
  const float* val = (const float*)d_in[2];
  float* out = (float*)d_out;
  sgm_kernel<<<B_, 512, 0, stream>>>(mem, key, val, out);
}

// Round 14
// 1029.046 us; speedup vs baseline: 1.0617x; 1.0617x over previous
//
#include <hip/hip_runtime.h>
#include <math.h>

#define B_   64
#define S_   1024
#define DK_  128
#define DV_  128
#define LR_    0.1f
#define THR_   0.1f
#define ITEMP_ 10.0f
#define EPS_   1e-6f

template<int CTRL>
__device__ __forceinline__ float dpp_add(float x) {
  int t = __builtin_amdgcn_update_dpp(0, __float_as_int(x), CTRL, 0xf, 0xf, true);
  return x + __int_as_float(t);
}
__device__ __forceinline__ float wave_sum64(float x) {
  x = dpp_add<0x111>(x); x = dpp_add<0x112>(x); x = dpp_add<0x114>(x);
  x = dpp_add<0x118>(x); x = dpp_add<0x142>(x); x = dpp_add<0x143>(x);
  return __int_as_float(__builtin_amdgcn_readlane(__float_as_int(x), 63));
}
// butterfly sum over the 8 slice-lanes (lane&7): all 8 lanes get the total
__device__ __forceinline__ float oct_sum_all(float x) {
  x = dpp_add<0xB1>(x);   // xor1 (quad_perm [1,0,3,2])
  x = dpp_add<0x4E>(x);   // xor2 (quad_perm [2,3,0,1])
  int t = __builtin_amdgcn_ds_swizzle(__float_as_int(x), 0x101F); // xor4
  return x + __int_as_float(t);
}
__device__ __forceinline__ float dot4(float4 a, float4 b) {
  return fmaf(a.x, b.x, fmaf(a.y, b.y, fmaf(a.z, b.z, a.w * b.w)));
}
__device__ __forceinline__ float4 upd4(float4 m, float a, float4 k) {
  return make_float4(fmaf(-a, k.x, m.x), fmaf(-a, k.y, m.y),
                     fmaf(-a, k.z, m.z), fmaf(-a, k.w, m.w));
}
#define PIN4(v) asm volatile("" : "+v"(v.x), "+v"(v.y), "+v"(v.z), "+v"(v.w))

__device__ __forceinline__ void gll16(const float* g, float* l) {
  __builtin_amdgcn_global_load_lds(
      (const __attribute__((address_space(1))) unsigned int*)g,
      (__attribute__((address_space(3))) unsigned int*)l, 16, 0, 0);
}

__global__ __launch_bounds__(512, 1)
void sgm_kernel(const float* __restrict__ mem_in,
                const float* __restrict__ key,
                const float* __restrict__ value,
                float* __restrict__ out) {
  const int b    = blockIdx.x;
  const int tid  = threadIdx.x;
  const int rp   = tid >> 3;        // rowpair 0..63 -> rows 2rp, 2rp+1
  const int sl   = tid & 7;         // 16-col slice
  const int lane = tid & 63;
  const int wv   = tid >> 6;        // wave 0..7 (8 rowpairs each)

  // per-lane chunk rotation: register j holds column chunk (j+sl)&3 of the slice
  const int cc0 = sl & 3, cc1 = (sl+1) & 3, cc2 = (sl+2) & 3, cc3 = (sl+3) & 3;
  const int kbase4 = sl * 4;        // float4 index of slice base within a 128-row

  __shared__ float ldsK[8][DK_];
  __shared__ float ldsV[8][DV_];
  __shared__ float slotS[2][8];
  __shared__ float gateL[S_];

  // ---- m: rows r0=2rp (ma) and r1=2rp+1 (mb), 16 cols each, rotated chunks ----
  float4 ma0, ma1, ma2, ma3, mb0, mb1, mb2, mb3;
  {
    const float4* mp4 = reinterpret_cast<const float4*>(mem_in + (size_t)b*DV_*DK_);
    const int r0 = 2*rp, r1 = 2*rp+1;
    ma0 = mp4[r0*32 + kbase4 + cc0]; ma1 = mp4[r0*32 + kbase4 + cc1];
    ma2 = mp4[r0*32 + kbase4 + cc2]; ma3 = mp4[r0*32 + kbase4 + cc3];
    mb0 = mp4[r1*32 + kbase4 + cc0]; mb1 = mp4[r1*32 + kbase4 + cc1];
    mb2 = mp4[r1*32 + kbase4 + cc2]; mb3 = mp4[r1*32 + kbase4 + cc3];
  }

  const float* kb = key   + (size_t)b * S_ * DK_;
  const float* vb = value + (size_t)b * S_ * DV_;

  auto stage = [&](int j) {
    const int s8 = j & 7;
    if (wv == 0 && lane < 32) gll16(kb + (size_t)j*DK_ + lane*4, &ldsK[s8][0]);
    if (wv == 1 && lane < 32) gll16(vb + (size_t)j*DV_ + lane*4, &ldsV[s8][0]);
  };

  stage(0); stage(1); stage(2); stage(3);
  if (wv < 2) asm volatile("s_waitcnt vmcnt(0)" ::: "memory");
  __syncthreads();

  float4 kA0, kA1, kA2, kA3, kB0, kB1, kB2, kB3;
  kA0 = kA1 = kA2 = kA3 = make_float4(0.f, 0.f, 0.f, 0.f);   // k_{-1}

  // ---- prologue: k_0 into B, norms, raw = M_init . k_0 ----
  {
    const float4* kp = reinterpret_cast<const float4*>(&ldsK[0][0]);
    kB0 = kp[kbase4 + cc0]; kB1 = kp[kbase4 + cc1];
    kB2 = kp[kbase4 + cc2]; kB3 = kp[kbase4 + cc3];
    PIN4(kB0); PIN4(kB1); PIN4(kB2); PIN4(kB3);
  }
  float rinC, raw0, raw1, vC0, vC1;
  {
    float kk = dot4(kB0,kB0) + dot4(kB1,kB1) + dot4(kB2,kB2) + dot4(kB3,kB3);
    rinC = 1.0f / (sqrtf(oct_sum_all(kk)) + EPS_);
    float d0 = dot4(ma0,kB0) + dot4(ma1,kB1) + dot4(ma2,kB2) + dot4(ma3,kB3);
    float d1 = dot4(mb0,kB0) + dot4(mb1,kB1) + dot4(mb2,kB2) + dot4(mb3,kB3);
    raw0 = oct_sum_all(d0); raw1 = oct_sum_all(d1);
    float2 vv = *reinterpret_cast<const float2*>(&ldsV[0][2*rp]);
    vC0 = vv.x; vC1 = vv.y;
  }
  float dkC = 0.f, u1_0 = 0.f, u1_1 = 0.f, gPrev = 0.f, rinPrev = 0.f;

  // One step. Entry: KC=k_s regs, KO=k_{s-1} regs, m=M_{s-2}, raw=M_{s-2}.k_s.
  // Exit: m=M_{s-1}, KO=k_{s+1}, raw=M_{s-1}.k_{s+1}.
#define STEPBODY(s, KO0,KO1,KO2,KO3, KC0,KC1,KC2,KC3)                          \
  {                                                                            \
    const float c1 = gPrev * rinPrev;                                          \
    const float cd = c1 * dkC;                                                 \
    const float pred0 = rinC * fmaf(-cd, u1_0, raw0);                          \
    const float pred1 = rinC * fmaf(-cd, u1_1, raw1);                          \
    const float surp0 = pred0 - vC0, surp1 = pred1 - vC1;                      \
    const float ws = wave_sum64(fmaf(surp0, surp0, surp1 * surp1));            \
    if (lane == 0) slotS[(s) & 1][wv] = ws;                                    \
    const float uN0 = fmaf(LR_, surp0, pred0);                                 \
    const float uN1 = fmaf(LR_, surp1, pred1);                                 \
    const float a1_0 = c1 * u1_0, a1_1 = c1 * u1_1;                            \
    ma0 = upd4(ma0, a1_0, KO0); ma1 = upd4(ma1, a1_0, KO1);                    \
    ma2 = upd4(ma2, a1_0, KO2); ma3 = upd4(ma3, a1_0, KO3);                    \
    mb0 = upd4(mb0, a1_1, KO0); mb1 = upd4(mb1, a1_1, KO1);                    \
    mb2 = upd4(mb2, a1_1, KO2); mb3 = upd4(mb3, a1_1, KO3);                    \
    const int ns = ((s) + 1) & 7;                                              \
    {                                                                          \
      const float4* kp = reinterpret_cast<const float4*>(&ldsK[ns][0]);        \
      KO0 = kp[kbase4 + cc0]; KO1 = kp[kbase4 + cc1];                          \
      KO2 = kp[kbase4 + cc2]; KO3 = kp[kbase4 + cc3];                          \
      PIN4(KO0); PIN4(KO1); PIN4(KO2); PIN4(KO3);                              \
    }                                                                          \
    float kkl = dot4(KO0,KO0)+dot4(KO1,KO1)+dot4(KO2,KO2)+dot4(KO3,KO3);       \
    float dkl = dot4(KC0,KO0)+dot4(KC1,KO1)+dot4(KC2,KO2)+dot4(KC3,KO3);       \
    const float kkN = oct_sum_all(kkl);                                        \
    const float dkN = oct_sum_all(dkl);                                        \
    const float rinN = 1.0f / (sqrtf(kkN) + EPS_);                             \
    float d0 = dot4(ma0,KO0)+dot4(ma1,KO1)+dot4(ma2,KO2)+dot4(ma3,KO3);        \
    float d1 = dot4(mb0,KO0)+dot4(mb1,KO1)+dot4(mb2,KO2)+dot4(mb3,KO3);        \
    const float rawN0 = oct_sum_all(d0);                                       \
    const float rawN1 = oct_sum_all(d1);                                       \
    const float2 vvN = *reinterpret_cast<const float2*>(&ldsV[ns][2*rp]);      \
    if (((s) & 3) == 0) {                                                      \
      const int t0=(s)+4>S_-1?S_-1:(s)+4, t1=(s)+5>S_-1?S_-1:(s)+5;            \
      const int t2=(s)+6>S_-1?S_-1:(s)+6, t3=(s)+7>S_-1?S_-1:(s)+7;            \
      stage(t0); stage(t1); stage(t2); stage(t3);                              \
    }                                                                          \
    if ((((s) & 3) == 2) && wv < 2)                                            \
      asm volatile("s_waitcnt vmcnt(0)" ::: "memory");                         \
    asm volatile("s_waitcnt lgkmcnt(0)" ::: "memory");                         \
    __builtin_amdgcn_s_barrier();                                              \
    asm volatile("" ::: "memory");                                             \
    const float4 q0 = *reinterpret_cast<const float4*>(&slotS[(s) & 1][0]);    \
    const float4 q1 = *reinterpret_cast<const float4*>(&slotS[(s) & 1][4]);    \
    const float s2 = 0.125f * (((q0.x+q0.y)+(q0.z+q0.w)) +                     \
                               ((q1.x+q1.y)+(q1.z+q1.w)));                     \
    const float g = 1.0f / (1.0f + __expf((THR_ - sqrtf(s2)) * ITEMP_));       \
    if (tid == 0) gateL[s] = g;                                                \
    gPrev = g; rinPrev = rinC; rinC = rinN; dkC = dkN;                         \
    u1_0 = uN0; u1_1 = uN1; raw0 = rawN0; raw1 = rawN1;                        \
    vC0 = vvN.x; vC1 = vvN.y;                                                  \
  }

  for (int s = 0; s < S_; s += 2) {
    STEPBODY(s,     kA0,kA1,kA2,kA3, kB0,kB1,kB2,kB3);
    STEPBODY(s + 1, kB0,kB1,kB2,kB3, kA0,kA1,kA2,kA3);
  }
#undef STEPBODY

  // final pending update for step S-1: k_{1023} lives in ldsK[7]
  {
    const float a1_0 = (gPrev * rinPrev) * u1_0;
    const float a1_1 = (gPrev * rinPrev) * u1_1;
    const float4* kp = reinterpret_cast<const float4*>(&ldsK[7][0]);
    const float4 f0 = kp[kbase4 + cc0], f1 = kp[kbase4 + cc1];
    const float4 f2 = kp[kbase4 + cc2], f3 = kp[kbase4 + cc3];
    ma0 = upd4(ma0, a1_0, f0); ma1 = upd4(ma1, a1_0, f1);
    ma2 = upd4(ma2, a1_0, f2); ma3 = upd4(ma3, a1_0, f3);
    mb0 = upd4(mb0, a1_1, f0); mb1 = upd4(mb1, a1_1, f1);
    mb2 = upd4(mb2, a1_1, f2); mb3 = upd4(mb3, a1_1, f3);
  }

  __syncthreads();

  {
    float4* op4 = reinterpret_cast<float4*>(out + (size_t)b*DV_*DK_);
    const int r0 = 2*rp, r1 = 2*rp+1;
    op4[r0*32 + kbase4 + cc0] = ma0; op4[r0*32 + kbase4 + cc1] = ma1;
    op4[r0*32 + kbase4 + cc2] = ma2; op4[r0*32 + kbase4 + cc3] = ma3;
    op4[r1*32 + kbase4 + cc0] = mb0; op4[r1*32 + kbase4 + cc1] = mb1;
    op4[r1*32 + kbase4 + cc2] = mb2; op4[r1*32 + kbase4 + cc3] = mb3;
  }
  float* go = out + (size_t)B_ * DV_ * DK_ + (size_t)b * S_;
  reinterpret_cast<float2*>(go)[tid] = reinterpret_cast<const float2*>(gateL)[tid];
}

extern "C" void kernel_launch(void* const* d_in, const int* in_sizes, int n_in,
                              void* d_out, int out_size, void* d_ws, size_t ws_size,
                              hipStream_t stream) {
  const float* mem = (const float*)d_in[0];
  const float* key = (const float*)d_in[1];
  const float* val = (const float*)d_in[2];
  float* out = (float*)d_out;
  sgm_kernel<<<B_, 512, 0, stream>>>(mem, key, val, out);
}

// Round 15
// 823.476 us; speedup vs baseline: 1.3268x; 1.2496x over previous
//
#include <hip/hip_runtime.h>
#include <math.h>

#define B_    64
#define S_    1024
#define DK_   128
#define DV_   128
#define T_    16
#define NC_   (S_ / T_)       // 64 chunks
#define LR_   0.1f
#define LRP1_ 1.1f            // 1 + LR
#define THR_  0.1f
#define ITEMP_ 10.0f
#define EPS_  1e-6f

// ---- DPP helpers ----
template<int CTRL>
__device__ __forceinline__ float dpp_add(float x) {
  int t = __builtin_amdgcn_update_dpp(0, __float_as_int(x), CTRL, 0xf, 0xf, true);
  return x + __int_as_float(t);
}
__device__ __forceinline__ float wave_sum64(float x) {
  x = dpp_add<0x111>(x); x = dpp_add<0x112>(x); x = dpp_add<0x114>(x);
  x = dpp_add<0x118>(x); x = dpp_add<0x142>(x); x = dpp_add<0x143>(x);
  return __int_as_float(__builtin_amdgcn_readlane(__float_as_int(x), 63));
}
__device__ __forceinline__ float quad_sum4(float x) {  // all 4 quad lanes get quad total
  x = dpp_add<0xB1>(x); x = dpp_add<0x4E>(x); return x;
}
__device__ __forceinline__ float rdlane(float v, int l) {
  return __int_as_float(__builtin_amdgcn_readlane(__float_as_int(v), l));
}
__device__ __forceinline__ void gll16(const float* g, float* l) {
  __builtin_amdgcn_global_load_lds(
      (const __attribute__((address_space(1))) unsigned int*)g,
      (__attribute__((address_space(3))) unsigned int*)l, 16, 0, 0);
}

__global__ __launch_bounds__(256, 1)
void sgm_kernel(const float* __restrict__ mem_in,
                const float* __restrict__ key,
                const float* __restrict__ value,
                float* __restrict__ out) {
  const int b    = blockIdx.x;
  const int tid  = threadIdx.x;
  const int rp   = tid >> 2;      // 0..63 -> owns rows rp and rp+64
  const int q    = tid & 3;       // 32-col quarter
  const int lane = tid & 63;
  const int wv   = tid >> 6;      // wave 0..3
  const int r0   = rp, r1 = rp + 64;

  // rotation: register i holds float4 chunk q*8 + ((i+2q)&7) of a 128-float row
  int cmap[8];
  #pragma unroll
  for (int i = 0; i < 8; ++i) cmap[i] = q * 8 + ((i + 2 * q) & 7);

  __shared__ __align__(16) float kS[2][T_][DK_];   // 16KB  k double buffer
  __shared__ __align__(16) float vS[2][T_][DV_];   // 16KB  v double buffer
  __shared__ __align__(16) float rawL[T_][DK_];    // 8KB   raw_t vectors
  __shared__ __align__(16) float cuL[T_][DK_];     // 8KB   cu_t vectors
  __shared__ __align__(16) float G[T_][T_];        // 1KB   Gram (j<=t valid)
  __shared__ __align__(16) float gateL[S_];        // 4KB

  // ---- M into registers: 2 rows x 32 cols ----
  float4 ma[8], mb[8];
  {
    const float4* Mp = reinterpret_cast<const float4*>(mem_in + (size_t)b * DV_ * DK_);
    #pragma unroll
    for (int i = 0; i < 8; ++i) { ma[i] = Mp[r0 * 32 + cmap[i]]; mb[i] = Mp[r1 * 32 + cmap[i]]; }
  }

  const float* kb = key   + (size_t)b * S_ * DK_;
  const float* vb = value + (size_t)b * S_ * DV_;

  auto stage = [&](int cc) {   // stage chunk cc into parity cc&1
    if (wv == 0 && lane < 32) {
      #pragma unroll
      for (int t = 0; t < T_; ++t)
        gll16(kb + (size_t)(cc * T_ + t) * DK_ + lane * 4, &kS[cc & 1][t][0]);
    }
    if (wv == 1 && lane < 32) {
      #pragma unroll
      for (int t = 0; t < T_; ++t)
        gll16(vb + (size_t)(cc * T_ + t) * DV_ + lane * 4, &vS[cc & 1][t][0]);
    }
  };

  auto applyUpdate = [&](int pb) {   // M -= sum_j cu_j (x) k_j   (chunk in parity pb)
    #pragma unroll
    for (int j = 0; j < T_; ++j) {
      const float cu0 = cuL[j][r0];
      const float cu1 = cuL[j][r1];
      const float4* kj = reinterpret_cast<const float4*>(&kS[pb][j][0]);
      #pragma unroll
      for (int i = 0; i < 8; ++i) {
        const float4 kv = kj[cmap[i]];
        ma[i].x = fmaf(-cu0, kv.x, ma[i].x); ma[i].y = fmaf(-cu0, kv.y, ma[i].y);
        ma[i].z = fmaf(-cu0, kv.z, ma[i].z); ma[i].w = fmaf(-cu0, kv.w, ma[i].w);
        mb[i].x = fmaf(-cu1, kv.x, mb[i].x); mb[i].y = fmaf(-cu1, kv.y, mb[i].y);
        mb[i].z = fmaf(-cu1, kv.z, mb[i].z); mb[i].w = fmaf(-cu1, kv.w, mb[i].w);
      }
    }
  };

  // prologue: stage chunk 0, drain, sync
  stage(0);
  if (wv < 2) asm volatile("s_waitcnt vmcnt(0)" ::: "memory");
  __syncthreads();

  for (int c = 0; c < NC_; ++c) {
    const int cb = c & 1;

    // ---- A: apply previous chunk's rank-16 update ----
    if (c > 0) applyUpdate((c - 1) & 1);
    asm volatile("s_waitcnt lgkmcnt(0)" ::: "memory");
    __builtin_amdgcn_s_barrier();                   // bar1: A's reads done
    asm volatile("" ::: "memory");
    if (c + 1 < NC_) stage(c + 1);                  // overwrites parity (c+1)&1

    // ---- B: raw_t = M . k_t  (+ wave0 computes kk diag) ----
    #pragma unroll
    for (int t = 0; t < T_; ++t) {
      const float4* kt = reinterpret_cast<const float4*>(&kS[cb][t][0]);
      float a0 = 0.f, a1 = 0.f, b0 = 0.f, b1 = 0.f;
      #pragma unroll
      for (int i = 0; i < 8; ++i) {
        const float4 kv = kt[cmap[i]];
        a0 = fmaf(ma[i].x, kv.x, a0); a1 = fmaf(ma[i].y, kv.y, a1);
        a0 = fmaf(ma[i].z, kv.z, a0); a1 = fmaf(ma[i].w, kv.w, a1);
        b0 = fmaf(mb[i].x, kv.x, b0); b1 = fmaf(mb[i].y, kv.y, b1);
        b0 = fmaf(mb[i].z, kv.z, b0); b1 = fmaf(mb[i].w, kv.w, b1);
      }
      const float dr0 = quad_sum4(a0 + a1);
      const float dr1 = quad_sum4(b0 + b1);
      if (q == 0) { rawL[t][r0] = dr0; rawL[t][r1] = dr1; }
      if (rp == t) {        // only wave 0 has rp<16: kk_t
        float k0 = 0.f, k1 = 0.f;
        #pragma unroll
        for (int i = 0; i < 8; ++i) {
          const float4 kv = kt[cmap[i]];
          k0 = fmaf(kv.x, kv.x, k0); k1 = fmaf(kv.y, kv.y, k1);
          k0 = fmaf(kv.z, kv.z, k0); k1 = fmaf(kv.w, kv.w, k1);
        }
        const float kk = quad_sum4(k0 + k1);
        if (q == 0) G[t][t] = kk;
      }
    }

    // ---- Gram: strict pairs j<t (120), 2 lanes per pair (64-dim halves) ----
    {
      const int p = tid >> 1, h = tid & 1;
      if (p < 120) {
        int t = 1, pp = p;
        while (pp >= t) { pp -= t; ++t; }           // p -> (t, j=pp), j<t
        const int j = pp;
        const float4* kj4 = reinterpret_cast<const float4*>(&kS[cb][j][h * 64]);
        const float4* kt4 = reinterpret_cast<const float4*>(&kS[cb][t][h * 64]);
        float acc0 = 0.f, acc1 = 0.f;
        #pragma unroll
        for (int i = 0; i < 16; ++i) {
          const int ii = (i + p) & 15;
          const float4 x = kj4[ii], y = kt4[ii];
          acc0 = fmaf(x.x, y.x, acc0); acc1 = fmaf(x.y, y.y, acc1);
          acc0 = fmaf(x.z, y.z, acc0); acc1 = fmaf(x.w, y.w, acc1);
        }
        float acc = acc0 + acc1;
        int sw = __builtin_amdgcn_update_dpp(0, __float_as_int(acc), 0xB1, 0xf, 0xf, true);
        const float tot = acc + __int_as_float(sw); // pair-lanes combined
        if (h == 0) G[j][t] = tot;
      }
    }

    asm volatile("s_waitcnt lgkmcnt(0)" ::: "memory");
    __builtin_amdgcn_s_barrier();                   // bar2: raw/G visible
    asm volatile("" ::: "memory");

    // ---- serial phase: 16 gates, redundant in every wave, no barriers ----
    {
      const int sj = lane & 15;
      float Gr[T_];
      #pragma unroll
      for (int t = 0; t < T_; ++t) Gr[t] = G[sj][t];     // lane j holds G[j][*]
      const float kkd = G[sj][sj];
      const float rinv = 1.0f / (sqrtf(kkd) + EPS_);      // lane j holds rin_j
      float cu0[T_], cu1[T_];
      #pragma unroll
      for (int t = 0; t < T_; ++t) {
        const float rin_t = rdlane(rinv, t);
        float y0 = 0.f, y1 = 0.f;
        #pragma unroll
        for (int j = 0; j < T_; ++j) {
          if (j < t) {
            const float gjt = rdlane(Gr[t], j);           // G[j][t], uniform
            y0 = fmaf(gjt, cu0[j], y0);
            y1 = fmaf(gjt, cu1[j], y1);
          }
        }
        const float raw0 = rawL[t][lane], raw1 = rawL[t][lane + 64];
        const float v0 = vS[cb][t][lane], v1 = vS[cb][t][lane + 64];
        const float pred0 = rin_t * (raw0 - y0);
        const float pred1 = rin_t * (raw1 - y1);
        const float s0 = pred0 - v0, s1 = pred1 - v1;
        const float s2 = wave_sum64(fmaf(s0, s0, s1 * s1));
        const float g = 1.0f / (1.0f + __expf((THR_ - sqrtf(s2)) * ITEMP_));
        if (tid == 0) gateL[c * T_ + t] = g;
        const float ct = g * rin_t;
        const float u0 = fmaf(LRP1_, pred0, -(LR_ * v0));
        const float u1 = fmaf(LRP1_, pred1, -(LR_ * v1));
        cu0[t] = ct * u0; cu1[t] = ct * u1;
        if (wv == 0) { cuL[t][lane] = cu0[t]; cuL[t][lane + 64] = cu1[t]; }
      }
    }

    asm volatile("s_waitcnt lgkmcnt(0)" ::: "memory");
    if (wv < 2) asm volatile("s_waitcnt vmcnt(0)" ::: "memory");  // staged c+1 landed
    __builtin_amdgcn_s_barrier();                   // bar3: cuL visible
    asm volatile("" ::: "memory");
  }

  // final rank-16 update for the last chunk
  applyUpdate((NC_ - 1) & 1);

  // ---- outputs ----
  {
    float4* Op = reinterpret_cast<float4*>(out + (size_t)b * DV_ * DK_);
    #pragma unroll
    for (int i = 0; i < 8; ++i) { Op[r0 * 32 + cmap[i]] = ma[i]; Op[r1 * 32 + cmap[i]] = mb[i]; }
    float4* Gp = reinterpret_cast<float4*>(out + (size_t)B_ * DV_ * DK_ + (size_t)b * S_);
    Gp[tid] = reinterpret_cast<const float4*>(gateL)[tid];
  }
}

extern "C" void kernel_launch(void* const* d_in, const int* in_sizes, int n_in,
                              void* d_out, int out_size, void* d_ws, size_t ws_size,
                              hipStream_t stream) {
  const float* mem = (const float*)d_in[0];
  const float* key = (const float*)d_in[1];
  const float* val = (const float*)d_in[2];
  float* out = (float*)d_out;
  sgm_kernel<<<B_, 256, 0, stream>>>(mem, key, val, out);
}

// Round 16
// 797.238 us; speedup vs baseline: 1.3705x; 1.0329x over previous
//
#include <hip/hip_runtime.h>
#include <math.h>

#define B_    64
#define S_    1024
#define DK_   128
#define DV_   128
#define T_    16
#define NC_   (S_ / T_)       // 64 chunks
#define LR_   0.1f
#define LRP1_ 1.1f            // 1 + LR
#define THR_  0.1f
#define ITEMP_ 10.0f
#define EPS_  1e-6f

// ---- DPP helpers ----
template<int CTRL>
__device__ __forceinline__ float dpp_add(float x) {
  int t = __builtin_amdgcn_update_dpp(0, __float_as_int(x), CTRL, 0xf, 0xf, true);
  return x + __int_as_float(t);
}
__device__ __forceinline__ float wave_sum64(float x) {
  x = dpp_add<0x111>(x); x = dpp_add<0x112>(x); x = dpp_add<0x114>(x);
  x = dpp_add<0x118>(x); x = dpp_add<0x142>(x); x = dpp_add<0x143>(x);
  return __int_as_float(__builtin_amdgcn_readlane(__float_as_int(x), 63));
}
__device__ __forceinline__ float quad_sum4(float x) {  // all 4 quad lanes get quad total
  x = dpp_add<0xB1>(x); x = dpp_add<0x4E>(x); return x;
}
__device__ __forceinline__ float rdlane(float v, int l) {
  return __int_as_float(__builtin_amdgcn_readlane(__float_as_int(v), l));
}
__device__ __forceinline__ void gll16(const float* g, float* l) {
  __builtin_amdgcn_global_load_lds(
      (const __attribute__((address_space(1))) unsigned int*)g,
      (__attribute__((address_space(3))) unsigned int*)l, 16, 0, 0);
}

__global__ __launch_bounds__(512, 1)
void sgm_kernel(const float* __restrict__ mem_in,
                const float* __restrict__ key,
                const float* __restrict__ value,
                float* __restrict__ out) {
  const int b    = blockIdx.x;
  const int tid  = threadIdx.x;
  const int rp   = tid >> 2;      // row 0..127
  const int q    = tid & 3;       // 32-col quarter
  const int lane = tid & 63;
  const int wv   = tid >> 6;      // wave 0..7

  // rotation: register i holds float4 chunk q*8 + ((i+2q)&7) of a 128-float row
  int cmap[8];
  #pragma unroll
  for (int i = 0; i < 8; ++i) cmap[i] = q * 8 + ((i + 2 * q) & 7);

  __shared__ __align__(16) float kS[2][T_][DK_];   // k double buffer
  __shared__ __align__(16) float vS[2][T_][DV_];   // v double buffer
  __shared__ __align__(16) float rawL[T_][DK_];    // raw_t vectors
  __shared__ __align__(16) float cuL[T_][DK_];     // cu_t vectors
  __shared__ __align__(16) float GT[T_][T_];       // GT[t][j] = k_j . k_t  (j<=t)
  __shared__ __align__(16) float gateL[S_];

  // ---- M into registers: 1 row x 32 cols ----
  float4 ma[8];
  {
    const float4* Mp = reinterpret_cast<const float4*>(mem_in + (size_t)b * DV_ * DK_);
    #pragma unroll
    for (int i = 0; i < 8; ++i) ma[i] = Mp[rp * 32 + cmap[i]];
  }

  const float* kb = key   + (size_t)b * S_ * DK_;
  const float* vb = value + (size_t)b * S_ * DV_;

  auto stage = [&](int cc) {   // stage chunk cc into parity cc&1
    if (wv == 0 && lane < 32) {
      #pragma unroll
      for (int t = 0; t < T_; ++t)
        gll16(kb + (size_t)(cc * T_ + t) * DK_ + lane * 4, &kS[cc & 1][t][0]);
    }
    if (wv == 1 && lane < 32) {
      #pragma unroll
      for (int t = 0; t < T_; ++t)
        gll16(vb + (size_t)(cc * T_ + t) * DV_ + lane * 4, &vS[cc & 1][t][0]);
    }
  };

  auto applyUpdate = [&](int pb) {   // M -= sum_j cu_j (x) k_j
    #pragma unroll
    for (int j = 0; j < T_; ++j) {
      const float cu0 = cuL[j][rp];
      const float4* kj = reinterpret_cast<const float4*>(&kS[pb][j][0]);
      #pragma unroll
      for (int i = 0; i < 8; ++i) {
        const float4 kv = kj[cmap[i]];
        ma[i].x = fmaf(-cu0, kv.x, ma[i].x); ma[i].y = fmaf(-cu0, kv.y, ma[i].y);
        ma[i].z = fmaf(-cu0, kv.z, ma[i].z); ma[i].w = fmaf(-cu0, kv.w, ma[i].w);
      }
    }
  };

  stage(0);
  if (wv < 2) asm volatile("s_waitcnt vmcnt(0)" ::: "memory");
  __syncthreads();

  for (int c = 0; c < NC_; ++c) {
    const int cb = c & 1;

    // ---- A: apply previous chunk's rank-16 update ----
    if (c > 0) applyUpdate((c - 1) & 1);
    asm volatile("s_waitcnt lgkmcnt(0)" ::: "memory");
    __builtin_amdgcn_s_barrier();                   // bar1: A's reads done
    asm volatile("" ::: "memory");
    if (c + 1 < NC_) stage(c + 1);

    // ---- B: raw_t = M . k_t  (+ diag kk via rp==t quads) ----
    #pragma unroll
    for (int t = 0; t < T_; ++t) {
      const float4* kt = reinterpret_cast<const float4*>(&kS[cb][t][0]);
      float a0 = 0.f, a1 = 0.f;
      #pragma unroll
      for (int i = 0; i < 8; ++i) {
        const float4 kv = kt[cmap[i]];
        a0 = fmaf(ma[i].x, kv.x, a0); a1 = fmaf(ma[i].y, kv.y, a1);
        a0 = fmaf(ma[i].z, kv.z, a0); a1 = fmaf(ma[i].w, kv.w, a1);
      }
      const float dr = quad_sum4(a0 + a1);
      if (q == 0) rawL[t][rp] = dr;
      if (rp == t) {
        float k0 = 0.f, k1 = 0.f;
        #pragma unroll
        for (int i = 0; i < 8; ++i) {
          const float4 kv = kt[cmap[i]];
          k0 = fmaf(kv.x, kv.x, k0); k1 = fmaf(kv.y, kv.y, k1);
          k0 = fmaf(kv.z, kv.z, k0); k1 = fmaf(kv.w, kv.w, k1);
        }
        const float kk = quad_sum4(k0 + k1);
        if (q == 0) GT[t][t] = kk;
      }
    }

    // ---- Gram: strict pairs j<t (120), 4 lanes per pair (32-dim quarters) ----
    {
      const int p = tid >> 2, h = tid & 3;
      if (p < 120) {
        int t = 1, pp = p;
        while (pp >= t) { pp -= t; ++t; }           // p -> (t, j=pp), j<t
        const int j = pp;
        const float4* kj4 = reinterpret_cast<const float4*>(&kS[cb][j][h * 32]);
        const float4* kt4 = reinterpret_cast<const float4*>(&kS[cb][t][h * 32]);
        float acc0 = 0.f, acc1 = 0.f;
        #pragma unroll
        for (int i = 0; i < 8; ++i) {
          const int ii = (i + p) & 7;
          const float4 x = kj4[ii], y = kt4[ii];
          acc0 = fmaf(x.x, y.x, acc0); acc1 = fmaf(x.y, y.y, acc1);
          acc0 = fmaf(x.z, y.z, acc0); acc1 = fmaf(x.w, y.w, acc1);
        }
        const float tot = quad_sum4(acc0 + acc1);
        if (h == 0) GT[t][j] = tot;
      }
    }

    asm volatile("s_waitcnt lgkmcnt(0)" ::: "memory");
    __builtin_amdgcn_s_barrier();                   // bar2: raw/GT visible
    asm volatile("" ::: "memory");

    // ---- serial phase: 16 gates, redundant per wave, operands preloaded ----
    {
      const int sj = lane & 15;
      float Gr[T_], rT0[T_], rT1[T_], vT0[T_], vT1[T_];
      #pragma unroll
      for (int t = 0; t < T_; ++t) {
        Gr[t]  = GT[t][sj];                // lane sj holds G[j=sj][t]
        rT0[t] = rawL[t][lane];  rT1[t] = rawL[t][lane + 64];
        vT0[t] = vS[cb][t][lane]; vT1[t] = vS[cb][t][lane + 64];
      }
      const float rinv = 1.0f / (sqrtf(GT[sj][sj]) + EPS_);  // lane j holds rin_j
      float cu0[T_], cu1[T_];
      #pragma unroll
      for (int t = 0; t < T_; ++t) {
        const float rin_t = rdlane(rinv, t);
        float y0 = 0.f, y1 = 0.f;
        #pragma unroll
        for (int j = 0; j < T_; ++j) {
          if (j < t) {
            const float gjt = rdlane(Gr[t], j);
            y0 = fmaf(gjt, cu0[j], y0);
            y1 = fmaf(gjt, cu1[j], y1);
          }
        }
        const float pred0 = rin_t * (rT0[t] - y0);
        const float pred1 = rin_t * (rT1[t] - y1);
        const float s0 = pred0 - vT0[t], s1 = pred1 - vT1[t];
        const float s2 = wave_sum64(fmaf(s0, s0, s1 * s1));
        const float g = 1.0f / (1.0f + __expf((THR_ - sqrtf(s2)) * ITEMP_));
        if (tid == 0) gateL[c * T_ + t] = g;
        const float ct = g * rin_t;
        const float u0 = fmaf(LRP1_, pred0, -(LR_ * vT0[t]));
        const float u1 = fmaf(LRP1_, pred1, -(LR_ * vT1[t]));
        cu0[t] = ct * u0; cu1[t] = ct * u1;
        if (wv == 0) { cuL[t][lane] = cu0[t]; cuL[t][lane + 64] = cu1[t]; }
      }
    }

    asm volatile("s_waitcnt lgkmcnt(0)" ::: "memory");
    if (wv < 2) asm volatile("s_waitcnt vmcnt(0)" ::: "memory");  // staged c+1 landed
    __builtin_amdgcn_s_barrier();                   // bar3: cuL visible
    asm volatile("" ::: "memory");
  }

  applyUpdate((NC_ - 1) & 1);

  // ---- outputs ----
  {
    float4* Op = reinterpret_cast<float4*>(out + (size_t)b * DV_ * DK_);
    #pragma unroll
    for (int i = 0; i < 8; ++i) Op[rp * 32 + cmap[i]] = ma[i];
    float2* Gp = reinterpret_cast<float2*>(out + (size_t)B_ * DV_ * DK_ + (size_t)b * S_);
    Gp[tid] = reinterpret_cast<const float2*>(gateL)[tid];
  }
}

extern "C" void kernel_launch(void* const* d_in, const int* in_sizes, int n_in,
                              void* d_out, int out_size, void* d_ws, size_t ws_size,
                              hipStream_t stream) {
  const float* mem = (const float*)d_in[0];
  const float* key = (const float*)d_in[1];
  const float* val = (const float*)d_in[2];
  float* out = (float*)d_out;
  sgm_kernel<<<B_, 512, 0, stream>>>(mem, key, val, out);
}

// Round 17
// 663.346 us; speedup vs baseline: 1.6471x; 1.2018x over previous
//
#include <hip/hip_runtime.h>
#include <math.h>

#define B_    64
#define S_    1024
#define DK_   128
#define DV_   128
#define T_    16
#define NC_   (S_ / T_)
#define LR_   0.1f
#define LRP1_ 1.1f
#define THR_  0.1f
#define ITEMP_ 10.0f
#define EPS_  1e-6f

template<int CTRL>
__device__ __forceinline__ float dpp_add(float x) {
  int t = __builtin_amdgcn_update_dpp(0, __float_as_int(x), CTRL, 0xf, 0xf, true);
  return x + __int_as_float(t);
}
__device__ __forceinline__ float wave_sum64(float x) {
  x = dpp_add<0x111>(x); x = dpp_add<0x112>(x); x = dpp_add<0x114>(x);
  x = dpp_add<0x118>(x); x = dpp_add<0x142>(x); x = dpp_add<0x143>(x);
  return __int_as_float(__builtin_amdgcn_readlane(__float_as_int(x), 63));
}
// sum over the 16 lanes of a DPP row; result valid in lane 15 of each row
__device__ __forceinline__ float row16_sum(float x) {
  x = dpp_add<0x111>(x); x = dpp_add<0x112>(x);
  x = dpp_add<0x114>(x); x = dpp_add<0x118>(x);
  return x;
}
__device__ __forceinline__ float quad_sum4(float x) {
  x = dpp_add<0xB1>(x); x = dpp_add<0x4E>(x); return x;
}
__device__ __forceinline__ float rdlane(float v, int l) {
  return __int_as_float(__builtin_amdgcn_readlane(__float_as_int(v), l));
}
__device__ __forceinline__ float dot4(float4 a, float4 b) {
  return fmaf(a.x, b.x, fmaf(a.y, b.y, fmaf(a.z, b.z, a.w * b.w)));
}
__device__ __forceinline__ void gll16(const float* g, float* l) {
  __builtin_amdgcn_global_load_lds(
      (const __attribute__((address_space(1))) unsigned int*)g,
      (__attribute__((address_space(3))) unsigned int*)l, 16, 0, 0);
}

__global__ __launch_bounds__(512, 2)
void sgm_kernel(const float* __restrict__ mem_in,
                const float* __restrict__ key,
                const float* __restrict__ value,
                float* __restrict__ out) {
  const int b    = blockIdx.x;
  const int tid  = threadIdx.x;
  const int g    = tid >> 4;      // rowgroup 0..31 -> rows 4g..4g+3
  const int h    = tid & 15;      // colgroup -> float4 idx h and 16+h
  const int lane = tid & 63;
  const int wv   = tid >> 6;

  __shared__ __align__(16) float kS[2][T_][DK_];
  __shared__ __align__(16) float vS[2][T_][DV_];
  __shared__ __align__(16) float rawL[T_][DK_];
  __shared__ __align__(16) float cuL[T_][DK_];
  __shared__ __align__(16) float GT[T_][T_];     // GT[t][j] = k_j.k_t (j<=t)
  __shared__ __align__(16) float gateL[S_];

  // ---- M: 4 rows x 8 cols (float4 idx h and 16+h per row) ----
  float4 mA[4], mB[4];
  {
    const float4* Mp = reinterpret_cast<const float4*>(mem_in + (size_t)b * DV_ * DK_);
    #pragma unroll
    for (int rr = 0; rr < 4; ++rr) {
      mA[rr] = Mp[(4*g + rr) * 32 + h];
      mB[rr] = Mp[(4*g + rr) * 32 + 16 + h];
    }
  }

  const float* kb = key   + (size_t)b * S_ * DK_;
  const float* vb = value + (size_t)b * S_ * DV_;

  auto stage = [&](int cc) {
    if (wv == 0 && lane < 32) {
      #pragma unroll
      for (int t = 0; t < T_; ++t)
        gll16(kb + (size_t)(cc * T_ + t) * DK_ + lane * 4, &kS[cc & 1][t][0]);
    }
    if (wv == 1 && lane < 32) {
      #pragma unroll
      for (int t = 0; t < T_; ++t)
        gll16(vb + (size_t)(cc * T_ + t) * DV_ + lane * 4, &vS[cc & 1][t][0]);
    }
  };

  auto applyUpdate = [&](int pb) {   // M -= sum_j cu_j (x) k_j
    #pragma unroll
    for (int j = 0; j < T_; ++j) {
      const float4* kj = reinterpret_cast<const float4*>(&kS[pb][j][0]);
      const float4 kx = kj[h], ky = kj[16 + h];
      const float4 cu = *reinterpret_cast<const float4*>(&cuL[j][4 * g]);
      const float c[4] = {cu.x, cu.y, cu.z, cu.w};
      #pragma unroll
      for (int rr = 0; rr < 4; ++rr) {
        mA[rr].x = fmaf(-c[rr], kx.x, mA[rr].x); mA[rr].y = fmaf(-c[rr], kx.y, mA[rr].y);
        mA[rr].z = fmaf(-c[rr], kx.z, mA[rr].z); mA[rr].w = fmaf(-c[rr], kx.w, mA[rr].w);
        mB[rr].x = fmaf(-c[rr], ky.x, mB[rr].x); mB[rr].y = fmaf(-c[rr], ky.y, mB[rr].y);
        mB[rr].z = fmaf(-c[rr], ky.z, mB[rr].z); mB[rr].w = fmaf(-c[rr], ky.w, mB[rr].w);
      }
    }
  };

  stage(0);
  if (wv < 2) asm volatile("s_waitcnt vmcnt(0)" ::: "memory");
  __syncthreads();

  for (int c = 0; c < NC_; ++c) {
    const int cb = c & 1;

    if (c > 0) applyUpdate((c - 1) & 1);
    asm volatile("s_waitcnt lgkmcnt(0)" ::: "memory");
    __builtin_amdgcn_s_barrier();                    // bar1
    asm volatile("" ::: "memory");
    if (c + 1 < NC_) stage(c + 1);

    // ---- raw_t = M . k_t ----
    #pragma unroll
    for (int t = 0; t < T_; ++t) {
      const float4* kt = reinterpret_cast<const float4*>(&kS[cb][t][0]);
      const float4 kx = kt[h], ky = kt[16 + h];
      float a0 = dot4(mA[0], kx) + dot4(mB[0], ky);
      float a1 = dot4(mA[1], kx) + dot4(mB[1], ky);
      float a2 = dot4(mA[2], kx) + dot4(mB[2], ky);
      float a3 = dot4(mA[3], kx) + dot4(mB[3], ky);
      a0 = row16_sum(a0); a1 = row16_sum(a1);
      a2 = row16_sum(a2); a3 = row16_sum(a3);
      if (h == 15)
        *reinterpret_cast<float4*>(&rawL[t][4 * g]) = make_float4(a0, a1, a2, a3);
    }

    // ---- diag kk_t: waves 0-3 (g = 0..15 maps to t) ----
    if (g < T_) {
      const float4* kt = reinterpret_cast<const float4*>(&kS[cb][g][0]);
      const float4 kx = kt[h], ky = kt[16 + h];
      float a = dot4(kx, kx) + dot4(ky, ky);
      a = row16_sum(a);
      if (h == 15) GT[g][g] = a;
    }

    // ---- Gram strict lower: 120 pairs x 4 lanes (disjoint bank-quads) ----
    {
      const int p = tid >> 2, c4 = tid & 3;
      if (p < 120) {
        int t = 1, pp = p;
        while (pp >= t) { pp -= t; ++t; }
        const int j = pp;
        const float4* kj4 = reinterpret_cast<const float4*>(&kS[cb][j][0]);
        const float4* kt4 = reinterpret_cast<const float4*>(&kS[cb][t][0]);
        float acc = 0.f;
        #pragma unroll
        for (int w = 0; w < 8; ++w)
          acc += dot4(kj4[c4 + 4 * w], kt4[c4 + 4 * w]);
        const float tot = quad_sum4(acc);
        if (c4 == 0) GT[t][j] = tot;
      }
    }

    asm volatile("s_waitcnt lgkmcnt(0)" ::: "memory");
    __builtin_amdgcn_s_barrier();                    // bar2
    asm volatile("" ::: "memory");

    // ---- serial phase: 16 gates (redundant per wave); lane holds dims 2l,2l+1 ----
    {
      const int sj = lane & 15;
      float Gr[T_];
      float2 rv[T_], vv[T_];
      #pragma unroll
      for (int t = 0; t < T_; ++t) {
        Gr[t] = GT[t][sj];
        rv[t] = *reinterpret_cast<const float2*>(&rawL[t][2 * lane]);
        vv[t] = *reinterpret_cast<const float2*>(&vS[cb][t][2 * lane]);
      }
      const float rinv = 1.0f / (sqrtf(GT[sj][sj]) + EPS_);
      float cu0[T_], cu1[T_];
      #pragma unroll
      for (int t = 0; t < T_; ++t) {
        const float rin_t = rdlane(rinv, t);
        float y0 = 0.f, y1 = 0.f;
        #pragma unroll
        for (int j = 0; j < T_; ++j) {
          if (j < t) {
            const float gjt = rdlane(Gr[t], j);
            y0 = fmaf(gjt, cu0[j], y0);
            y1 = fmaf(gjt, cu1[j], y1);
          }
        }
        const float pred0 = rin_t * (rv[t].x - y0);
        const float pred1 = rin_t * (rv[t].y - y1);
        const float s0 = pred0 - vv[t].x, s1 = pred1 - vv[t].y;
        const float s2 = wave_sum64(fmaf(s0, s0, s1 * s1));
        const float gg = 1.0f / (1.0f + __expf((THR_ - sqrtf(s2)) * ITEMP_));
        if (tid == 0) gateL[c * T_ + t] = gg;
        const float ct = gg * rin_t;
        const float u0 = fmaf(LRP1_, pred0, -(LR_ * vv[t].x));
        const float u1 = fmaf(LRP1_, pred1, -(LR_ * vv[t].y));
        cu0[t] = ct * u0; cu1[t] = ct * u1;
        if (wv == 0)
          *reinterpret_cast<float2*>(&cuL[t][2 * lane]) = make_float2(cu0[t], cu1[t]);
      }
    }

    asm volatile("s_waitcnt lgkmcnt(0)" ::: "memory");
    if (wv < 2) asm volatile("s_waitcnt vmcnt(0)" ::: "memory");
    __builtin_amdgcn_s_barrier();                    // bar3
    asm volatile("" ::: "memory");
  }

  applyUpdate((NC_ - 1) & 1);

  {
    float4* Op = reinterpret_cast<float4*>(out + (size_t)b * DV_ * DK_);
    #pragma unroll
    for (int rr = 0; rr < 4; ++rr) {
      Op[(4*g + rr) * 32 + h] = mA[rr];
      Op[(4*g + rr) * 32 + 16 + h] = mB[rr];
    }
    float2* Gp = reinterpret_cast<float2*>(out + (size_t)B_ * DV_ * DK_ + (size_t)b * S_);
    Gp[tid] = reinterpret_cast<const float2*>(gateL)[tid];
  }
}

extern "C" void kernel_launch(void* const* d_in, const int* in_sizes, int n_in,
                              void* d_out, int out_size, void* d_ws, size_t ws_size,
                              hipStream_t stream) {
  const float* mem = (const float*)d_in[0];
  const float* key = (const float*)d_in[1];
  const float* val = (const float*)d_in[2];
  float* out = (float*)d_out;
  sgm_kernel<<<B_, 512, 0, stream>>>(mem, key, val, out);
}

// Round 18
// 589.225 us; speedup vs baseline: 1.8543x; 1.1258x over previous
//
#include <hip/hip_runtime.h>
#include <math.h>

#define B_    64
#define S_    1024
#define DK_   128
#define DV_   128
#define T_    16
#define NC_   (S_ / T_)
#define KP_   (DK_ + 4)    // padded LDS row stride: bank offset rotates 4 per row
#define LR_   0.1f
#define LRP1_ 1.1f
#define THR_  0.1f
#define ITEMP_ 10.0f
#define EPS_  1e-6f

template<int CTRL>
__device__ __forceinline__ float dpp_add(float x) {
  int t = __builtin_amdgcn_update_dpp(0, __float_as_int(x), CTRL, 0xf, 0xf, true);
  return x + __int_as_float(t);
}
__device__ __forceinline__ float wave_sum64(float x) {
  x = dpp_add<0x111>(x); x = dpp_add<0x112>(x); x = dpp_add<0x114>(x);
  x = dpp_add<0x118>(x); x = dpp_add<0x142>(x); x = dpp_add<0x143>(x);
  return __int_as_float(__builtin_amdgcn_readlane(__float_as_int(x), 63));
}
__device__ __forceinline__ float row16_sum(float x) {  // valid in lane15 of each row
  x = dpp_add<0x111>(x); x = dpp_add<0x112>(x);
  x = dpp_add<0x114>(x); x = dpp_add<0x118>(x);
  return x;
}
__device__ __forceinline__ float quad_sum4(float x) {
  x = dpp_add<0xB1>(x); x = dpp_add<0x4E>(x); return x;
}
__device__ __forceinline__ float rdlane(float v, int l) {
  return __int_as_float(__builtin_amdgcn_readlane(__float_as_int(v), l));
}
__device__ __forceinline__ float dot4(float4 a, float4 b) {
  return fmaf(a.x, b.x, fmaf(a.y, b.y, fmaf(a.z, b.z, a.w * b.w)));
}
__device__ __forceinline__ void gll16(const float* g, float* l) {
  __builtin_amdgcn_global_load_lds(
      (const __attribute__((address_space(1))) unsigned int*)g,
      (__attribute__((address_space(3))) unsigned int*)l, 16, 0, 0);
}

__global__ __launch_bounds__(512, 2)
void sgm_kernel(const float* __restrict__ mem_in,
                const float* __restrict__ key,
                const float* __restrict__ value,
                float* __restrict__ out) {
  const int b    = blockIdx.x;
  const int tid  = threadIdx.x;
  const int g    = tid >> 4;      // rowgroup 0..31 -> rows 4g..4g+3
  const int h    = tid & 15;      // colgroup -> float4 idx h and 16+h
  const int lane = tid & 63;
  const int wv   = tid >> 6;

  __shared__ __align__(16) float kS[2][T_][KP_];
  __shared__ __align__(16) float vS[2][T_][KP_];
  __shared__ __align__(16) float rawL[T_][DK_];
  __shared__ __align__(16) float cuL[T_][DK_];
  __shared__ __align__(16) float GT[T_][T_];     // GT[t][j] = k_j.k_t (j<=t)
  __shared__ __align__(16) float gateL[S_];

  float4 mA[4], mB[4];
  {
    const float4* Mp = reinterpret_cast<const float4*>(mem_in + (size_t)b * DV_ * DK_);
    #pragma unroll
    for (int rr = 0; rr < 4; ++rr) {
      mA[rr] = Mp[(4*g + rr) * 32 + h];
      mB[rr] = Mp[(4*g + rr) * 32 + 16 + h];
    }
  }

  const float* kb = key   + (size_t)b * S_ * DK_;
  const float* vb = value + (size_t)b * S_ * DV_;

  auto stage = [&](int cc) {
    if (wv == 0 && lane < 32) {
      #pragma unroll
      for (int t = 0; t < T_; ++t)
        gll16(kb + (size_t)(cc * T_ + t) * DK_ + lane * 4, &kS[cc & 1][t][0]);
    }
    if (wv == 1 && lane < 32) {
      #pragma unroll
      for (int t = 0; t < T_; ++t)
        gll16(vb + (size_t)(cc * T_ + t) * DV_ + lane * 4, &vS[cc & 1][t][0]);
    }
  };

  float4 kxR[16];   // current chunk's k, first-half float4 (col idx h) per t

  // M -= sum_j cu_j (x) k_j ; first half from kxR regs, second half from LDS
  auto applyUpdate = [&](int pb) {
    #pragma unroll
    for (int j = 0; j < T_; ++j) {
      const float4* kj = reinterpret_cast<const float4*>(&kS[pb][j][0]);
      const float4 ky = kj[16 + h];
      const float4 cu = *reinterpret_cast<const float4*>(&cuL[j][4 * g]);
      const float cc[4] = {cu.x, cu.y, cu.z, cu.w};
      #pragma unroll
      for (int rr = 0; rr < 4; ++rr) {
        mA[rr].x = fmaf(-cc[rr], kxR[j].x, mA[rr].x);
        mA[rr].y = fmaf(-cc[rr], kxR[j].y, mA[rr].y);
        mA[rr].z = fmaf(-cc[rr], kxR[j].z, mA[rr].z);
        mA[rr].w = fmaf(-cc[rr], kxR[j].w, mA[rr].w);
        mB[rr].x = fmaf(-cc[rr], ky.x, mB[rr].x);
        mB[rr].y = fmaf(-cc[rr], ky.y, mB[rr].y);
        mB[rr].z = fmaf(-cc[rr], ky.z, mB[rr].z);
        mB[rr].w = fmaf(-cc[rr], ky.w, mB[rr].w);
      }
    }
  };

  stage(0);
  if (wv < 2) asm volatile("s_waitcnt vmcnt(0)" ::: "memory");
  __syncthreads();

  for (int c = 0; c < NC_; ++c) {
    const int cb = c & 1;

    // ---- apply previous chunk's rank-16 update (kxR holds chunk c-1's k) ----
    if (c > 0) applyUpdate((c - 1) & 1);

    // ---- load new chunk's k first-halves into registers ----
    #pragma unroll
    for (int t = 0; t < T_; ++t)
      kxR[t] = reinterpret_cast<const float4*>(&kS[cb][t][0])[h];

    asm volatile("s_waitcnt lgkmcnt(0)" ::: "memory");
    __builtin_amdgcn_s_barrier();                    // bar1: old-parity reads done
    asm volatile("" ::: "memory");
    if (c + 1 < NC_) stage(c + 1);

    // ---- raw_t = M . k_t ----
    #pragma unroll
    for (int t = 0; t < T_; ++t) {
      const float4 ky = reinterpret_cast<const float4*>(&kS[cb][t][0])[16 + h];
      float a0 = dot4(mA[0], kxR[t]) + dot4(mB[0], ky);
      float a1 = dot4(mA[1], kxR[t]) + dot4(mB[1], ky);
      float a2 = dot4(mA[2], kxR[t]) + dot4(mB[2], ky);
      float a3 = dot4(mA[3], kxR[t]) + dot4(mB[3], ky);
      a0 = row16_sum(a0); a1 = row16_sum(a1);
      a2 = row16_sum(a2); a3 = row16_sum(a3);
      if (h == 15)
        *reinterpret_cast<float4*>(&rawL[t][4 * g]) = make_float4(a0, a1, a2, a3);
    }

    // ---- diag kk_t (waves 0-3, row g<16) ----
    if (g < T_) {
      const float4* kt = reinterpret_cast<const float4*>(&kS[cb][g][0]);
      const float4 kx = kt[h], ky = kt[16 + h];
      float a = dot4(kx, kx) + dot4(ky, ky);
      a = row16_sum(a);
      if (h == 15) GT[g][g] = a;
    }

    // ---- Gram strict lower: 120 pairs x 4 lanes (rows bank-rotated by pad) ----
    {
      const int p = tid >> 2, c4 = tid & 3;
      if (p < 120) {
        int t = 1, pp = p;
        while (pp >= t) { pp -= t; ++t; }
        const int j = pp;
        const float4* kj4 = reinterpret_cast<const float4*>(&kS[cb][j][0]);
        const float4* kt4 = reinterpret_cast<const float4*>(&kS[cb][t][0]);
        float acc = 0.f;
        #pragma unroll
        for (int w = 0; w < 8; ++w)
          acc += dot4(kj4[c4 + 4 * w], kt4[c4 + 4 * w]);
        const float tot = quad_sum4(acc);
        if (c4 == 0) GT[t][j] = tot;
      }
    }

    asm volatile("s_waitcnt lgkmcnt(0)" ::: "memory");
    __builtin_amdgcn_s_barrier();                    // bar2: raw/GT visible
    asm volatile("" ::: "memory");

    // ---- serial phase: wave 0 ONLY (sole consumers: cuL, gateL) ----
    if (wv == 0) {
      const int sj = lane & 15;
      float Gr[T_];
      #pragma unroll
      for (int t = 0; t < T_; ++t) Gr[t] = GT[t][sj];
      const float rinv = 1.0f / (sqrtf(GT[sj][sj]) + EPS_);
      float cu0[T_], cu1[T_];
      #pragma unroll
      for (int t = 0; t < T_; ++t) {
        const float rin_t = rdlane(rinv, t);
        float y0 = 0.f, y1 = 0.f;
        #pragma unroll
        for (int j = 0; j < T_; ++j) {
          if (j < t) {
            const float gjt = rdlane(Gr[t], j);
            y0 = fmaf(gjt, cu0[j], y0);
            y1 = fmaf(gjt, cu1[j], y1);
          }
        }
        const float2 rv = *reinterpret_cast<const float2*>(&rawL[t][2 * lane]);
        const float2 vv = *reinterpret_cast<const float2*>(&vS[cb][t][2 * lane]);
        const float pred0 = rin_t * (rv.x - y0);
        const float pred1 = rin_t * (rv.y - y1);
        const float s0 = pred0 - vv.x, s1 = pred1 - vv.y;
        const float s2 = wave_sum64(fmaf(s0, s0, s1 * s1));
        const float gg = 1.0f / (1.0f + __expf((THR_ - sqrtf(s2)) * ITEMP_));
        if (lane == 0) gateL[c * T_ + t] = gg;
        const float ct = gg * rin_t;
        const float u0 = fmaf(LRP1_, pred0, -(LR_ * vv.x));
        const float u1 = fmaf(LRP1_, pred1, -(LR_ * vv.y));
        cu0[t] = ct * u0; cu1[t] = ct * u1;
        *reinterpret_cast<float2*>(&cuL[t][2 * lane]) = make_float2(cu0[t], cu1[t]);
      }
    }

    asm volatile("s_waitcnt lgkmcnt(0)" ::: "memory");
    if (wv < 2) asm volatile("s_waitcnt vmcnt(0)" ::: "memory");
    __builtin_amdgcn_s_barrier();                    // bar3: cuL visible, stage landed
    asm volatile("" ::: "memory");
  }

  applyUpdate((NC_ - 1) & 1);

  {
    float4* Op = reinterpret_cast<float4*>(out + (size_t)b * DV_ * DK_);
    #pragma unroll
    for (int rr = 0; rr < 4; ++rr) {
      Op[(4*g + rr) * 32 + h] = mA[rr];
      Op[(4*g + rr) * 32 + 16 + h] = mB[rr];
    }
    float2* Gp = reinterpret_cast<float2*>(out + (size_t)B_ * DV_ * DK_ + (size_t)b * S_);
    Gp[tid] = reinterpret_cast<const float2*>(gateL)[tid];
  }
}

extern "C" void kernel_launch(void* const* d_in, const int* in_sizes, int n_in,
                              void* d_out, int out_size, void* d_ws, size_t ws_size,
                              hipStream_t stream) {
  const float* mem = (const float*)d_in[0];
  const float* key = (const float*)d_in[1];
  const float* val = (const float*)d_in[2];
  float* out = (float*)d_out;
  sgm_kernel<<<B_, 512, 0, stream>>>(mem, key, val, out);
}